// Round 2
// baseline (299.713 us; speedup 1.0000x reference)
//
#include <hip/hip_runtime.h>

#define CDIM 64
#define NDIM 4096
#define TILE 128

typedef __attribute__((ext_vector_type(8))) short bf16x8;
typedef __attribute__((ext_vector_type(4))) float f32x4;

__device__ __forceinline__ unsigned short f2bf(float x) {
    unsigned int u = __builtin_bit_cast(unsigned int, x);
    u += 0x7fffu + ((u >> 16) & 1u);          // round-to-nearest-even
    return (unsigned short)(u >> 16);
}
__device__ __forceinline__ float bf2f(unsigned short s) {
    unsigned int u = ((unsigned int)s) << 16;
    return __builtin_bit_cast(float, u);
}

// ---------------------------------------------------------------------------
// Prepass: A[b][c][n] f32  ->  At[b][n][c] bf16  (+ squared norms from the
// bf16-rounded values, so the main kernel's d = aa + bb - 2ab is exactly
// sum((a_bf - b_bf)^2) up to fp32 accumulation order).
// grid: (NDIM/64, batch, 2); block 256.
// ---------------------------------------------------------------------------
__global__ __launch_bounds__(256)
void prep_kernel(const float* __restrict__ A, const float* __restrict__ B,
                 unsigned short* __restrict__ At, unsigned short* __restrict__ Bt,
                 float* __restrict__ aa, float* __restrict__ bb) {
    const int t  = threadIdx.x;
    const int n0 = blockIdx.x * 64;
    const int bz = blockIdx.y;
    const bool isB = (blockIdx.z != 0);

    const float* src = (isB ? B : A) + (size_t)bz * CDIM * NDIM;
    unsigned short* dst = (isB ? Bt : At) + (size_t)bz * NDIM * CDIM;
    float* nrm = (isB ? bb : aa) + (size_t)bz * NDIM;

    __shared__ unsigned short T[64 * 72];   // [n][c], row = 144 B (16B-aligned)
    __shared__ float psum[64 * 4];

    // load f32 [c][n], convert, transpose into LDS [n][c]
    {
        const int nq = t & 15;      // n-quad: n = 4*nq + e
        const int c0 = t >> 4;      // c row 0..15
        for (int it = 0; it < 4; ++it) {
            const int c = c0 + 16 * it;
            f32x4 v = *(const f32x4*)(src + (size_t)c * NDIM + n0 + 4 * nq);
            for (int e = 0; e < 4; ++e)
                T[(4 * nq + e) * 72 + c] = f2bf(v[e]);
        }
    }
    __syncthreads();

    // norms from bf16 values
    {
        const int n = t & 63, p = t >> 6;
        float s = 0.f;
        for (int c = 16 * p; c < 16 * p + 16; ++c) {
            float v = bf2f(T[n * 72 + c]);
            s += v * v;
        }
        psum[n * 4 + p] = s;
    }
    __syncthreads();
    if (t < 64)
        nrm[n0 + t] = psum[t * 4] + psum[t * 4 + 1] + psum[t * 4 + 2] + psum[t * 4 + 3];

    // write transposed bf16 rows: row = 64 bf16 = 128 B contiguous
    for (int it = 0; it < 2; ++it) {
        const int row = (t >> 3) + 32 * it;
        const int ch  = t & 7;
        bf16x8 v = *(const bf16x8*)&T[row * 72 + ch * 8];
        *(bf16x8*)(dst + (size_t)(n0 + row) * CDIM + ch * 8) = v;
    }
}

// ---------------------------------------------------------------------------
// Main: 128x128 output tile per block. No LDS, no barriers. Fragments loaded
// straight from the L2-resident transposed bf16 tensors. MFMA operands are
// SWAPPED (B first) so D[row]=j, D[col]=i: each lane holds 4 consecutive j
// -> dwordx4 stores.
// ---------------------------------------------------------------------------
__global__ __launch_bounds__(256)
void distmap_main(const unsigned short* __restrict__ At,
                  const unsigned short* __restrict__ Bt,
                  const float* __restrict__ aa, const float* __restrict__ bb,
                  float* __restrict__ D) {
    const int t    = threadIdx.x;
    const int wv   = t >> 6;
    const int lane = t & 63;
    const int lm   = lane & 15;
    const int lq   = lane >> 4;          // 0..3
    const int j0   = blockIdx.x * TILE;
    const int i0   = blockIdx.y * TILE;
    const int bz   = blockIdx.z;

    const unsigned short* Ab = At + (size_t)bz * NDIM * CDIM;
    const unsigned short* Bb = Bt + (size_t)bz * NDIM * CDIM;
    const float* aab = aa + (size_t)bz * NDIM;
    const float* bbb = bb + (size_t)bz * NDIM;

    // A fragments: operand m = lane&15 -> i row; k-chunk = lq*8 (+32)
    bf16x8 afr[2][2];
    float  aav[2];
#pragma unroll
    for (int ti = 0; ti < 2; ++ti) {
        const int irow = i0 + (2 * wv + ti) * 16 + lm;
        const unsigned short* p = Ab + (size_t)irow * CDIM + lq * 8;
        afr[ti][0] = *(const bf16x8*)p;
        afr[ti][1] = *(const bf16x8*)(p + 32);
        aav[ti] = aab[irow];
    }

    f32x4 acc[2][8];
#pragma unroll
    for (int ti = 0; ti < 2; ++ti)
#pragma unroll
        for (int tj = 0; tj < 8; ++tj)
            acc[ti][tj] = (f32x4){0.f, 0.f, 0.f, 0.f};

#pragma unroll
    for (int tj = 0; tj < 8; ++tj) {
        const int jrow = j0 + tj * 16 + lm;
        const unsigned short* p = Bb + (size_t)jrow * CDIM + lq * 8;
        bf16x8 b0 = *(const bf16x8*)p;
        bf16x8 b1 = *(const bf16x8*)(p + 32);
        // swapped operands: D[row]=j, D[col]=i
        acc[0][tj] = __builtin_amdgcn_mfma_f32_16x16x32_bf16(b0, afr[0][0], acc[0][tj], 0, 0, 0);
        acc[0][tj] = __builtin_amdgcn_mfma_f32_16x16x32_bf16(b1, afr[0][1], acc[0][tj], 0, 0, 0);
        acc[1][tj] = __builtin_amdgcn_mfma_f32_16x16x32_bf16(b0, afr[1][0], acc[1][tj], 0, 0, 0);
        acc[1][tj] = __builtin_amdgcn_mfma_f32_16x16x32_bf16(b1, afr[1][1], acc[1][tj], 0, 0, 0);
    }

    // epilogue: d[i][j] = aa[i] + bb[j] - 2*ab
    // lane's i = i0+(2wv+ti)*16+lm (fixed), j = j0+tj*16+lq*4+r (r contiguous)
    float* Db = D + (size_t)bz * NDIM * NDIM;
#pragma unroll
    for (int tj = 0; tj < 8; ++tj) {
        const int jb = j0 + tj * 16 + lq * 4;
        f32x4 bbv = *(const f32x4*)(bbb + jb);
#pragma unroll
        for (int ti = 0; ti < 2; ++ti) {
            const int irow = i0 + (2 * wv + ti) * 16 + lm;
            f32x4 out;
#pragma unroll
            for (int r = 0; r < 4; ++r)
                out[r] = (aav[ti] + bbv[r]) - 2.0f * acc[ti][tj][r];
            *(f32x4*)(Db + (size_t)irow * NDIM + jb) = out;
        }
    }
}

extern "C" void kernel_launch(void* const* d_in, const int* in_sizes, int n_in,
                              void* d_out, int out_size, void* d_ws, size_t ws_size,
                              hipStream_t stream) {
    const float* a = (const float*)d_in[0];
    const float* b = (const float*)d_in[1];
    float* out = (float*)d_out;
    const int batch = in_sizes[0] / (CDIM * NDIM);   // = 4

    unsigned short* At = (unsigned short*)d_ws;
    unsigned short* Bt = At + (size_t)batch * NDIM * CDIM;
    float* aa = (float*)(Bt + (size_t)batch * NDIM * CDIM);
    float* bb = aa + (size_t)batch * NDIM;

    prep_kernel<<<dim3(NDIM / 64, batch, 2), dim3(256), 0, stream>>>(a, b, At, Bt, aa, bb);
    distmap_main<<<dim3(NDIM / TILE, NDIM / TILE, batch), dim3(256), 0, stream>>>(At, Bt, aa, bb, out);
}